// Round 10
// baseline (221.154 us; speedup 1.0000x reference)
//
#include <hip/hip_runtime.h>
#include <cstdint>

#define BATCH  4
#define SLEN   4096
#define FDIM   64
#define KDIM   32
#define KSPLIT 8
#define CHUNK  (SLEN / KSPLIT)   // 512
#define QBLK   256               // queries per attn block
#define NQB    (SLEN / QBLK)     // 16 q-blocks per batch

typedef __attribute__((ext_vector_type(8))) short bf16x8;
typedef __attribute__((ext_vector_type(4))) float f32x4;

static __device__ __forceinline__ short f2bf(float f) {
    union { float f; unsigned u; } v; v.f = f;
    unsigned r = v.u + 0x7fffu + ((v.u >> 16) & 1u);   // RNE
    return (short)(r >> 16);
}
static __device__ __forceinline__ float bf2f(short s) {
    union { unsigned u; float f; } v;
    v.u = ((unsigned)(unsigned short)s) << 16;
    return v.f;
}
// pack2bf(a,b) -> uint, low short = bf16(a), high short = bf16(b), RNE.
static __device__ __forceinline__ unsigned pack2bf(float a, float b) {
    union { float f; unsigned u; } x, y; x.f = a; y.f = b;
    unsigned ra = x.u + 0x7fffu + ((x.u >> 16) & 1u);
    unsigned rb = y.u + 0x7fffu + ((y.u >> 16) & 1u);
    return __builtin_amdgcn_perm(rb, ra, 0x07060302u);  // {rb.hi, ra.hi}
}

// ---------------------------------------------------------------------------
// Fused prep:
//  (a) M -> bf16 hi/lo Dekker split (K side) and (M*log2e) hi/lo (Q side)
//  (b) V = X@W (fp32)
//  (c) Vt[b][f][s0 + perm(c)] = bf16(V); perm within each 32-key group:
//      c = 16h + 4q + r -> slot = 8q + 4h + r (PV A-operand k-order, so the
//      attn V B-frag is ONE 16-byte load)
//  (d) zero the split-k completion counters (re-poisoned to 0xAA each launch)
// ---------------------------------------------------------------------------
__global__ __launch_bounds__(256) void prep(const float4* __restrict__ M4,
                                            ushort4* __restrict__ H4,
                                            ushort4* __restrict__ L4,
                                            ushort4* __restrict__ QH4,
                                            ushort4* __restrict__ QL4,
                                            const float* __restrict__ X,
                                            const float4* __restrict__ W4,
                                            float4* __restrict__ V4,
                                            short* __restrict__ Vt,
                                            int* __restrict__ cnt) {
    if (blockIdx.y == 0 && threadIdx.x == 0)           // gridDim.x = 64
        cnt[blockIdx.x] = 0;                           // 64 counters

    const int blk = blockIdx.y * gridDim.x + blockIdx.x;   // 0..255
    const float LOG2E = 1.4426950408889634f;
#pragma unroll
    for (int r = 0; r < 2; ++r) {
        int i = (blk * 2 + r) * 256 + threadIdx.x;         // [0, 131072)
        float4 m = M4[i];
        ushort4 h, l, sh, sl;
        h.x = (unsigned short)f2bf(m.x); l.x = (unsigned short)f2bf(m.x - bf2f((short)h.x));
        h.y = (unsigned short)f2bf(m.y); l.y = (unsigned short)f2bf(m.y - bf2f((short)h.y));
        h.z = (unsigned short)f2bf(m.z); l.z = (unsigned short)f2bf(m.z - bf2f((short)h.z));
        h.w = (unsigned short)f2bf(m.w); l.w = (unsigned short)f2bf(m.w - bf2f((short)h.w));
        float sx = m.x * LOG2E, sy = m.y * LOG2E, sz = m.z * LOG2E, sw = m.w * LOG2E;
        sh.x = (unsigned short)f2bf(sx); sl.x = (unsigned short)f2bf(sx - bf2f((short)sh.x));
        sh.y = (unsigned short)f2bf(sy); sl.y = (unsigned short)f2bf(sy - bf2f((short)sh.y));
        sh.z = (unsigned short)f2bf(sz); sl.z = (unsigned short)f2bf(sz - bf2f((short)sh.z));
        sh.w = (unsigned short)f2bf(sw); sl.w = (unsigned short)f2bf(sw - bf2f((short)sh.w));
        H4[i] = h; L4[i] = l; QH4[i] = sh; QL4[i] = sl;
    }
    // --- (b)+(c) XW + transpose ---
    __shared__ float t[64][65];
    const int b  = blockIdx.y;
    const int s0 = blockIdx.x * 64;
    const int o4 = threadIdx.x & 15;
    const int rq = threadIdx.x >> 4;
#pragma unroll
    for (int half = 0; half < 4; ++half) {
        int r = half * 16 + rq;
        const float* __restrict__ xr = X + ((size_t)b * SLEN + s0 + r) * FDIM;
        float4 acc = make_float4(0.f, 0.f, 0.f, 0.f);
#pragma unroll
        for (int f = 0; f < FDIM; ++f) {
            float4 w = W4[f * 16 + o4];
            float  x = xr[f];
            acc.x = fmaf(x, w.x, acc.x);
            acc.y = fmaf(x, w.y, acc.y);
            acc.z = fmaf(x, w.z, acc.z);
            acc.w = fmaf(x, w.w, acc.w);
        }
        V4[((size_t)b * SLEN + s0 + r) * 16 + o4] = acc;
        t[r][o4 * 4 + 0] = acc.x;
        t[r][o4 * 4 + 1] = acc.y;
        t[r][o4 * 4 + 2] = acc.z;
        t[r][o4 * 4 + 3] = acc.w;
    }
    __syncthreads();
    const int c0 = threadIdx.x & 63;
    const int r0 = threadIdx.x >> 6;
    const int pc = (c0 & 32) | (((c0 >> 2) & 3) << 3) | (((c0 >> 4) & 1) << 2)
                 | (c0 & 3);
#pragma unroll
    for (int i = 0; i < 16; ++i) {
        int f = r0 + i * 4;
        Vt[((size_t)b * FDIM + f) * SLEN + s0 + pc] = f2bf(t[c0][f]);
    }
}

// ---------------------------------------------------------------------------
// Attention partials + fused split-k finalize.
// Block = 4 waves = 256 queries (QT=4 per wave). NO LDS staging, NO barriers
// in the key loop: K/V fragments read directly from global (L2-resident
// slab, XCD-swizzled). At QT=4 the frag traffic is ~268 MB total (~29
// B/cyc/CU) -- under the measured L1 saturation that sank the QT=1 variant.
// QK operand-swapped (A=K, B=Q): C = [key][q]; exp2'd scores feed the PV
// A-operand directly (Q pre-scaled by log2e). l via ones-B MFMA.
// Additive partials (max s*log2e ~104 < fp32 overflow).
// After writing partials: release fence + per-(b,qblk) atomic counter; the
// last-arriving block combines all 8 partials -> out (no separate kernel).
// ---------------------------------------------------------------------------
__global__ __launch_bounds__(256, 2) void attn_mfma(const short* __restrict__ Mhi,
                                                    const short* __restrict__ Mlo,
                                                    const short* __restrict__ Qhi,
                                                    const short* __restrict__ Qlo,
                                                    const short* __restrict__ Vt,
                                                    float* __restrict__ accP,
                                                    float* __restrict__ lP,
                                                    const float4* __restrict__ V4,
                                                    const float4* __restrict__ bias4,
                                                    float4* __restrict__ out4,
                                                    int* __restrict__ cnt) {
    const int bid  = blockIdx.x;                 // 512 blocks
    const int xcd  = bid & 7;
    const int slot = bid >> 3;                   // 0..63
    const int g    = xcd + 8 * (slot >> 4);      // slab (b,ks) id [0,32)
    const int qblk = slot & 15;                  // q-block [0,16)
    const int b    = g >> 3;
    const int ks   = g & 7;

    const int tid  = threadIdx.x;
    const int wave = tid >> 6;
    const int lane = tid & 63;
    const int col  = lane & 15;
    const int quad = lane >> 4;
    const int qbase = qblk * QBLK + wave * 64;
    const int k0    = ks * CHUNK;

    const short* __restrict__ Mbh = Mhi + (size_t)b * SLEN * KDIM;
    const short* __restrict__ Mbl = Mlo + (size_t)b * SLEN * KDIM;
    const short* __restrict__ Qbh = Qhi + (size_t)b * SLEN * KDIM;
    const short* __restrict__ Qbl = Qlo + (size_t)b * SLEN * KDIM;
    const short* __restrict__ Vb  = Vt  + (size_t)b * FDIM * SLEN;

    // Q fragments (B-operand: n = q, k = quad*8+j), pre-scaled by log2e.
    bf16x8 Qh[4], Ql[4];
#pragma unroll
    for (int tq = 0; tq < 4; ++tq) {
        int qo = (qbase + tq * 16 + col) * KDIM + quad * 8;
        Qh[tq] = *(const bf16x8*)(Qbh + qo);
        Ql[tq] = *(const bf16x8*)(Qbl + qo);
    }

    const bf16x8 ONES = (bf16x8){0x3F80, 0x3F80, 0x3F80, 0x3F80,
                                 0x3F80, 0x3F80, 0x3F80, 0x3F80};

    f32x4 accf[4][4], accl[4];
#pragma unroll
    for (int tq = 0; tq < 4; ++tq) {
        accl[tq] = (f32x4){0.f, 0.f, 0.f, 0.f};
#pragma unroll
        for (int fg = 0; fg < 4; ++fg) accf[tq][fg] = (f32x4){0.f, 0.f, 0.f, 0.f};
    }

#pragma unroll 1
    for (int kt = k0; kt < k0 + CHUNK; kt += 32) {
        // K fragments: 16 consecutive 64B rows per tile -> coalesced b128.
        const bf16x8 Kh0 = *(const bf16x8*)(Mbh + (kt + col) * KDIM + quad * 8);
        const bf16x8 Kh1 = *(const bf16x8*)(Mbh + (kt + 16 + col) * KDIM + quad * 8);
        const bf16x8 Kl0 = *(const bf16x8*)(Mbl + (kt + col) * KDIM + quad * 8);
        const bf16x8 Kl1 = *(const bf16x8*)(Mbl + (kt + 16 + col) * KDIM + quad * 8);
        // V B-frags: one b128 per fg (pre-permuted key order covers K=32).
        bf16x8 Vv[4];
#pragma unroll
        for (int fg = 0; fg < 4; ++fg)
            Vv[fg] = *(const bf16x8*)(Vb + (fg * 16 + col) * SLEN + kt + quad * 8);

#pragma unroll
        for (int tq = 0; tq < 4; ++tq) {
            f32x4 z = (f32x4){0.f, 0.f, 0.f, 0.f};
            f32x4 c0 = __builtin_amdgcn_mfma_f32_16x16x32_bf16(Kh0, Ql[tq], z, 0, 0, 0);
            f32x4 c1 = __builtin_amdgcn_mfma_f32_16x16x32_bf16(Kh1, Ql[tq], z, 0, 0, 0);
            c0 = __builtin_amdgcn_mfma_f32_16x16x32_bf16(Kl0, Qh[tq], c0, 0, 0, 0);
            c1 = __builtin_amdgcn_mfma_f32_16x16x32_bf16(Kl1, Qh[tq], c1, 0, 0, 0);
            c0 = __builtin_amdgcn_mfma_f32_16x16x32_bf16(Kh0, Qh[tq], c0, 0, 0, 0);
            c1 = __builtin_amdgcn_mfma_f32_16x16x32_bf16(Kh1, Qh[tq], c1, 0, 0, 0);

            float e0 = __builtin_amdgcn_exp2f(fmaxf(c0[0], 0.f));
            float e1 = __builtin_amdgcn_exp2f(fmaxf(c0[1], 0.f));
            float e2 = __builtin_amdgcn_exp2f(fmaxf(c0[2], 0.f));
            float e3 = __builtin_amdgcn_exp2f(fmaxf(c0[3], 0.f));
            float e4 = __builtin_amdgcn_exp2f(fmaxf(c1[0], 0.f));
            float e5 = __builtin_amdgcn_exp2f(fmaxf(c1[1], 0.f));
            float e6 = __builtin_amdgcn_exp2f(fmaxf(c1[2], 0.f));
            float e7 = __builtin_amdgcn_exp2f(fmaxf(c1[3], 0.f));

            union { unsigned u[4]; bf16x8 v; } pa;
            pa.u[0] = pack2bf(e0, e1);
            pa.u[1] = pack2bf(e2, e3);
            pa.u[2] = pack2bf(e4, e5);
            pa.u[3] = pack2bf(e6, e7);

            accl[tq] = __builtin_amdgcn_mfma_f32_16x16x32_bf16(pa.v, ONES,
                                                               accl[tq], 0, 0, 0);
#pragma unroll
            for (int fg = 0; fg < 4; ++fg)
                accf[tq][fg] = __builtin_amdgcn_mfma_f32_16x16x32_bf16(
                    pa.v, Vv[fg], accf[tq][fg], 0, 0, 0);
        }
    }

    // Partials. C layout: row q = quad*4+j, col f = fg*16+col.
#pragma unroll
    for (int tq = 0; tq < 4; ++tq) {
#pragma unroll
        for (int j = 0; j < 4; ++j) {
            int q = qbase + tq * 16 + quad * 4 + j;
            size_t base = ((size_t)b * SLEN + q) * KSPLIT + ks;
            float* __restrict__ op = accP + base * FDIM;
#pragma unroll
            for (int fg = 0; fg < 4; ++fg)
                op[fg * 16 + col] = accf[tq][fg][j];
            if (col == 0) lP[base] = accl[tq][j];
        }
    }

    // ---- split-k completion: last arriver for (b,qblk) finalizes ----
    __threadfence();                             // release our stores
    __syncthreads();                             // all threads' stores fenced
    __shared__ int lastFlag;
    if (tid == 0) {
        int old = atomicAdd(&cnt[b * NQB + qblk], 1);   // device-scope
        lastFlag = (old == KSPLIT - 1) ? 1 : 0;
    }
    __syncthreads();
    if (lastFlag) {
        __threadfence();                         // acquire: invalidate stale
        const int o4   = tid & 15;
        const int rsub = tid >> 4;               // 0..15
        const float4 bb = bias4[o4];
        const float4* __restrict__ accP4 = (const float4*)accP;
#pragma unroll 1
        for (int it = 0; it < 16; ++it) {
            size_t row = (size_t)b * SLEN + qblk * QBLK + it * 16 + rsub;
            float nx = 0.f, ny = 0.f, nz = 0.f, nw = 0.f, den = 0.f;
#pragma unroll
            for (int k = 0; k < KSPLIT; ++k) {
                float4 a = accP4[(row * KSPLIT + k) * 16 + o4];
                nx += a.x; ny += a.y; nz += a.z; nw += a.w;
                den += lP[row * KSPLIT + k];
            }
            float rr = 1.f / den;
            float4 v = V4[row * 16 + o4];
            float4 o;
            o.x = v.x + nx * rr + bb.x;
            o.y = v.y + ny * rr + bb.y;
            o.z = v.z + nz * rr + bb.z;
            o.w = v.w + nw * rr + bb.w;
            out4[row * 16 + o4] = o;
        }
    }
}

// ---------------------------------------------------------------------------
extern "C" void kernel_launch(void* const* d_in, const int* in_sizes, int n_in,
                              void* d_out, int out_size, void* d_ws, size_t ws_size,
                              hipStream_t stream) {
    const float* X    = (const float*)d_in[0];   // [4,4096,64]
    const float* M    = (const float*)d_in[1];   // [4,4096,32]
    const float* W    = (const float*)d_in[2];   // [64,64]
    const float* bias = (const float*)d_in[3];   // [64]
    float* out = (float*)d_out;                  // [4,4096,64]

    const size_t vElems = (size_t)BATCH * SLEN * FDIM;   // 1,048,576
    const size_t mElems = (size_t)BATCH * SLEN * KDIM;   //   524,288
    const size_t rows   = (size_t)BATCH * SLEN;          //    16,384

    float* Vf   = (float*)d_ws;
    float* accP = Vf + vElems;
    float* lP   = accP + vElems * KSPLIT;
    short* Mhi  = (short*)(lP + rows * KSPLIT);
    short* Mlo  = Mhi + mElems;
    short* Qhi  = Mlo + mElems;
    short* Qlo  = Qhi + mElems;
    short* Vt   = Qlo + mElems;
    int*   cnt  = (int*)(Vt + vElems);           // 64 counters

    prep<<<dim3(SLEN / 64, BATCH), 256, 0, stream>>>(
        (const float4*)M, (ushort4*)Mhi, (ushort4*)Mlo,
        (ushort4*)Qhi, (ushort4*)Qlo,
        X, (const float4*)W, (float4*)Vf, Vt, cnt);

    attn_mfma<<<dim3(BATCH * KSPLIT * NQB), 256, 0, stream>>>(
        Mhi, Mlo, Qhi, Qlo, Vt, accP, lP,
        (const float4*)Vf, (const float4*)bias, (float4*)out, cnt);
}